// Round 2
// baseline (359.896 us; speedup 1.0000x reference)
//
#include <hip/hip_runtime.h>
#include <hip/hip_bf16.h>
#include <math.h>

// Problem constants (fixed by setup_inputs)
#define BB   256
#define DIN  2048
#define DD   512
#define CC   1000
#define NN   50000
#define MM   (NN + BB)     // 50256
#define FILTER_K 100
#define SLOT 512           // per-class scatter capacity; max real count ~85+256

// ---------------- workspace layout (float elements) ----------------
// [z | p | cnt] are contiguous so ONE memset zeroes all split-K accumulators.
#define Z_OFF     0                         // z:   [256][512]
#define P_OFF     (Z_OFF + BB*DD)           // p:   [256][1000]
#define CNT_OFF   (P_OFF + BB*CC)           // cnt: [1024] int
#define ENTN_OFF  (CNT_OFF + 1024)          // ent_new: [256]
#define CLS_OFF   (ENTN_OFF + BB)           // cls: [256] int
#define ENTS_OFF  (CLS_OFF + BB)            // ent_s: [1000][512]
#define IDXS_OFF  (ENTS_OFF + CC*SLOT)      // idx_s: [1000][512] int
#define WN_OFF    (IDXS_OFF + CC*SLOT)      // wn:  [1000][512]
#define MEMSET_FLOATS (BB*DD + BB*CC + 1024)

// GEMM tiling: 64x128 block tile, 4x8 micro-tile (as 4 + 4 cols 64 apart to
// keep b128 LDS reads 2-way-conflict-free), BK=16, split-K via atomics.
#define BM 64
#define BN 128
#define BK 16

// ============ K1: C += A[M][K] @ B[K][N]  (split-K, atomic) ==============
__global__ __launch_bounds__(256, 2) void gemm_ab(
    const float* __restrict__ A, const float* __restrict__ B,
    float* __restrict__ C, int M, int N, int K, int klen) {
  __shared__ float As[BK][BM + 4];
  __shared__ float Bs[BK][BN + 4];
  const int tid = threadIdx.x;
  const int m0 = blockIdx.y * BM;
  const int n0 = blockIdx.x * BN;
  const int k0 = blockIdx.z * klen;
  const int ar = tid >> 2, ac = (tid & 3) * 4;   // A: 64 rows x 16 k
  const int br = tid >> 4, bc = (tid & 15) * 8;  // B: 16 k x 128 n
  const int tm = (tid >> 4) * 4;                 // 0..60
  const int tn = (tid & 15) * 4;                 // 0..60 (+64 for 2nd half)
  float acc[4][8] = {};
  for (int kk = 0; kk < klen; kk += BK) {
    float4 av  = *(const float4*)&A[(size_t)(m0 + ar) * K + (k0 + kk + ac)];
    float4 bv0 = *(const float4*)&B[(size_t)(k0 + kk + br) * N + (n0 + bc)];
    float4 bv1 = *(const float4*)&B[(size_t)(k0 + kk + br) * N + (n0 + bc + 4)];
    __syncthreads();
    As[ac + 0][ar] = av.x; As[ac + 1][ar] = av.y;
    As[ac + 2][ar] = av.z; As[ac + 3][ar] = av.w;
    *(float4*)&Bs[br][bc] = bv0;
    *(float4*)&Bs[br][bc + 4] = bv1;
    __syncthreads();
#pragma unroll
    for (int q = 0; q < BK; ++q) {
      float4 a  = *(const float4*)&As[q][tm];
      float4 b0 = *(const float4*)&Bs[q][tn];
      float4 b1 = *(const float4*)&Bs[q][tn + 64];
      float aa[4] = {a.x, a.y, a.z, a.w};
      float bb[8] = {b0.x, b0.y, b0.z, b0.w, b1.x, b1.y, b1.z, b1.w};
#pragma unroll
      for (int i = 0; i < 4; ++i)
#pragma unroll
        for (int j = 0; j < 8; ++j) acc[i][j] += aa[i] * bb[j];
    }
  }
#pragma unroll
  for (int i = 0; i < 4; ++i)
#pragma unroll
    for (int j = 0; j < 4; ++j) {
      atomicAdd(&C[(size_t)(m0 + tm + i) * N + (n0 + tn + j)], acc[i][j]);
      atomicAdd(&C[(size_t)(m0 + tm + i) * N + (n0 + 64 + tn + j)], acc[i][j + 4]);
    }
}

// ======== K2/K5: C += A[M][K] @ B[L][K]^T  (split-K, atomic, L-guard) ====
__global__ __launch_bounds__(256, 2) void gemm_abt(
    const float* __restrict__ A, const float* __restrict__ B,
    float* __restrict__ C, int M, int L, int K, int klen) {
  __shared__ float As[BK][BM + 4];
  __shared__ float Bs[BK][BN + 4];
  const int tid = threadIdx.x;
  const int m0 = blockIdx.y * BM;
  const int n0 = blockIdx.x * BN;
  const int k0 = blockIdx.z * klen;
  const int ar = tid >> 2, ac = (tid & 3) * 4;   // A: 64 rows x 16 k
  const int br = tid >> 2, bc = (tid & 3) * 4;   // B: 2 x (64 rows) x 16 k
  const int tm = (tid >> 4) * 4;
  const int tn = (tid & 15) * 4;
  float acc[4][8] = {};
  for (int kk = 0; kk < klen; kk += BK) {
    float4 av = *(const float4*)&A[(size_t)(m0 + ar) * K + (k0 + kk + ac)];
    float4 bv0 = make_float4(0.f, 0.f, 0.f, 0.f);
    float4 bv1 = make_float4(0.f, 0.f, 0.f, 0.f);
    if (n0 + br < L)
      bv0 = *(const float4*)&B[(size_t)(n0 + br) * K + (k0 + kk + bc)];
    if (n0 + 64 + br < L)
      bv1 = *(const float4*)&B[(size_t)(n0 + 64 + br) * K + (k0 + kk + bc)];
    __syncthreads();
    As[ac + 0][ar] = av.x; As[ac + 1][ar] = av.y;
    As[ac + 2][ar] = av.z; As[ac + 3][ar] = av.w;
    Bs[bc + 0][br] = bv0.x; Bs[bc + 1][br] = bv0.y;
    Bs[bc + 2][br] = bv0.z; Bs[bc + 3][br] = bv0.w;
    Bs[bc + 0][br + 64] = bv1.x; Bs[bc + 1][br + 64] = bv1.y;
    Bs[bc + 2][br + 64] = bv1.z; Bs[bc + 3][br + 64] = bv1.w;
    __syncthreads();
#pragma unroll
    for (int q = 0; q < BK; ++q) {
      float4 a  = *(const float4*)&As[q][tm];
      float4 b0 = *(const float4*)&Bs[q][tn];
      float4 b1 = *(const float4*)&Bs[q][tn + 64];
      float aa[4] = {a.x, a.y, a.z, a.w};
      float bb[8] = {b0.x, b0.y, b0.z, b0.w, b1.x, b1.y, b1.z, b1.w};
#pragma unroll
      for (int i = 0; i < 4; ++i)
#pragma unroll
        for (int j = 0; j < 8; ++j) acc[i][j] += aa[i] * bb[j];
    }
  }
#pragma unroll
  for (int i = 0; i < 4; ++i)
#pragma unroll
    for (int j = 0; j < 4; ++j) {
      int n = n0 + tn + j;
      if (n < L) atomicAdd(&C[(size_t)(m0 + tm + i) * L + n], acc[i][j]);
      int n2 = n0 + 64 + tn + j;
      if (n2 < L) atomicAdd(&C[(size_t)(m0 + tm + i) * L + n2], acc[i][j + 4]);
    }
}

// ====== per-row argmax + softmax entropy over p (bias applied here) ======
__global__ __launch_bounds__(256) void rowstats(
    const float* __restrict__ p, const float* __restrict__ bc,
    float* __restrict__ ent_new, int* __restrict__ cls) {
  const int b = blockIdx.x, tid = threadIdx.x;
  const int lane = tid & 63, wid = tid >> 6;
  const float* row = p + (size_t)b * CC;
  float r[4];
  float mv = -INFINITY; int mi = 0x7fffffff;
#pragma unroll
  for (int i = 0; i < 4; ++i) {
    int c = tid + 256 * i;
    r[i] = (c < CC) ? (row[c] + bc[c]) : -INFINITY;
    if (r[i] > mv) { mv = r[i]; mi = c; }   // ascending c: strict > keeps first
  }
#pragma unroll
  for (int o = 32; o > 0; o >>= 1) {
    float ov = __shfl_down(mv, o, 64);
    int oi = __shfl_down(mi, o, 64);
    if (ov > mv || (ov == mv && oi < mi)) { mv = ov; mi = oi; }
  }
  __shared__ float smv[4]; __shared__ int smi[4];
  if (lane == 0) { smv[wid] = mv; smi[wid] = mi; }
  __syncthreads();
  if (tid == 0) {
#pragma unroll
    for (int w = 1; w < 4; ++w)
      if (smv[w] > smv[0] || (smv[w] == smv[0] && smi[w] < smi[0])) {
        smv[0] = smv[w]; smi[0] = smi[w];
      }
  }
  __syncthreads();
  const float m = smv[0]; const int am = smi[0];
  float s = 0.f, t = 0.f;
#pragma unroll
  for (int i = 0; i < 4; ++i) {
    if (tid + 256 * i < CC) {
      float u = r[i] - m;
      float e = expf(u);
      s += e; t += u * e;
    }
  }
#pragma unroll
  for (int o = 32; o > 0; o >>= 1) {
    s += __shfl_down(s, o, 64);
    t += __shfl_down(t, o, 64);
  }
  __shared__ float ssum[4], tsum[4];
  if (lane == 0) { ssum[wid] = s; tsum[wid] = t; }
  __syncthreads();
  if (tid == 0) {
    float S = ssum[0] + ssum[1] + ssum[2] + ssum[3];
    float T = tsum[0] + tsum[1] + tsum[2] + tsum[3];
    ent_new[b] = logf(S) - T / S;
    cls[b] = am;
  }
}

// ========== direct scatter into fixed per-class slots (no scan) ==========
__global__ void scatter(const int* __restrict__ labels_idx,
                        const int* __restrict__ cls,
                        const float* __restrict__ ent_in,
                        const float* __restrict__ ent_new,
                        int* __restrict__ cnt,
                        float* __restrict__ ent_s, int* __restrict__ idx_s) {
  int m = blockIdx.x * blockDim.x + threadIdx.x;
  if (m >= MM) return;
  int c; float e;
  if (m < NN) { c = labels_idx[m]; e = ent_in[m]; }
  else        { c = cls[m - NN];   e = ent_new[m - NN]; }
  int pos = atomicAdd(&cnt[c], 1);
  if (pos < SLOT) {
    ent_s[(size_t)c * SLOT + pos] = e;
    idx_s[(size_t)c * SLOT + pos] = m;
  }
}

// ====== per-class: select K lowest-entropy rows, sum normalized rows =====
// Wave-per-row: no barriers in the streaming loop; full-wave shfl_xor reduce.
__global__ __launch_bounds__(256) void class_weights(
    const float* __restrict__ supports_in, const float* __restrict__ z,
    const float* __restrict__ ent_s, const int* __restrict__ idx_s,
    const int* __restrict__ cnt, float* __restrict__ wn) {
  const int c = blockIdx.x, tid = threadIdx.x;
  const int lane = tid & 63, wid = tid >> 6;
  int n = cnt[c]; if (n > SLOT) n = SLOT;

  __shared__ int sel[SLOT];
  __shared__ float se[SLOT];
  __shared__ int si[SLOT];
  int seln;
  if (n <= FILTER_K) {
    seln = n;
    for (int i = tid; i < n; i += 256) sel[i] = idx_s[(size_t)c * SLOT + i];
  } else {
    for (int i = tid; i < SLOT; i += 256) {
      if (i < n) { se[i] = ent_s[(size_t)c * SLOT + i]; si[i] = idx_s[(size_t)c * SLOT + i]; }
      else       { se[i] = INFINITY;                     si[i] = 0x7fffffff; }
    }
    __syncthreads();
    for (int k = 2; k <= SLOT; k <<= 1)
      for (int j = k >> 1; j > 0; j >>= 1) {
        for (int i = tid; i < SLOT; i += 256) {
          int ixj = i ^ j;
          if (ixj > i) {
            bool up = ((i & k) == 0);
            float e1 = se[i], e2 = se[ixj];
            int i1 = si[i], i2 = si[ixj];
            bool gt = (e1 > e2) || (e1 == e2 && i1 > i2);
            if (gt == up) { se[i] = e2; se[ixj] = e1; si[i] = i2; si[ixj] = i1; }
          }
        }
        __syncthreads();
      }
    seln = FILTER_K;
    for (int i = tid; i < FILTER_K; i += 256) sel[i] = si[i];
  }
  __syncthreads();

  // each wave streams whole rows; lane owns dims [lane*8, lane*8+8)
  float4 a0 = make_float4(0.f, 0.f, 0.f, 0.f), a1 = a0;
  for (int j = wid; j < seln; j += 4) {
    int ridx = sel[j];
    const float4* p4 = (const float4*)((ridx < NN)
        ? supports_in + (size_t)ridx * DD
        : z + (size_t)(ridx - NN) * DD);
    float4 v0 = p4[lane * 2], v1 = p4[lane * 2 + 1];
    float s = v0.x * v0.x + v0.y * v0.y + v0.z * v0.z + v0.w * v0.w
            + v1.x * v1.x + v1.y * v1.y + v1.z * v1.z + v1.w * v1.w;
#pragma unroll
    for (int o = 1; o < 64; o <<= 1) s += __shfl_xor(s, o, 64);
    float sc = 1.0f / fmaxf(sqrtf(s), 1e-12f);
    a0.x += v0.x * sc; a0.y += v0.y * sc; a0.z += v0.z * sc; a0.w += v0.w * sc;
    a1.x += v1.x * sc; a1.y += v1.y * sc; a1.z += v1.z * sc; a1.w += v1.w * sc;
  }

  __shared__ float part[4][DD];
  *(float4*)&part[wid][lane * 8] = a0;
  *(float4*)&part[wid][lane * 8 + 4] = a1;
  __syncthreads();
  const int d = tid * 2;
  float2 w;
  w.x = part[0][d] + part[1][d] + part[2][d] + part[3][d];
  w.y = part[0][d + 1] + part[1][d + 1] + part[2][d + 1] + part[3][d + 1];
  float ss = w.x * w.x + w.y * w.y;
#pragma unroll
  for (int o = 1; o < 64; o <<= 1) ss += __shfl_xor(ss, o, 64);
  __shared__ float tot[4];
  if (lane == 0) tot[wid] = ss;
  __syncthreads();
  float S = tot[0] + tot[1] + tot[2] + tot[3];
  float sc = 1.0f / fmaxf(sqrtf(S), 1e-12f);
  ((float2*)(wn + (size_t)c * DD))[tid] = make_float2(w.x * sc, w.y * sc);
}

// ============================ launcher ===================================
extern "C" void kernel_launch(void* const* d_in, const int* in_sizes, int n_in,
                              void* d_out, int out_size, void* d_ws, size_t ws_size,
                              hipStream_t stream) {
  (void)in_sizes; (void)n_in; (void)out_size; (void)ws_size;
  const float* x           = (const float*)d_in[0];
  const float* Wf          = (const float*)d_in[1];
  const float* Wc          = (const float*)d_in[2];
  const float* bc          = (const float*)d_in[3];
  const float* supports_in = (const float*)d_in[4];
  const float* ent_in      = (const float*)d_in[5];
  const int*   labels_idx  = (const int*)d_in[6];
  float* out = (float*)d_out;

  float* W = (float*)d_ws;
  float* z       = W + Z_OFF;
  float* p       = W + P_OFF;
  int*   cnt     = (int*)(W + CNT_OFF);
  float* ent_new = W + ENTN_OFF;
  int*   cls     = (int*)(W + CLS_OFF);
  float* ent_s   = W + ENTS_OFF;
  int*   idx_s   = (int*)(W + IDXS_OFF);
  float* wn      = W + WN_OFF;

  // one fused zero-init for all split-K accumulators + counters; one for out
  hipMemsetAsync(W, 0, (size_t)MEMSET_FLOATS * sizeof(float), stream);
  hipMemsetAsync(d_out, 0, (size_t)BB * CC * sizeof(float), stream);

  // z = x @ Wf   (M=256,N=512,K=2048) split-K 32
  gemm_ab<<<dim3(DD / BN, BB / BM, 32), 256, 0, stream>>>(
      x, Wf, z, BB, DD, DIN, DIN / 32);
  // p = z @ Wc^T (bias folded into rowstats), split-K 8
  gemm_abt<<<dim3((CC + BN - 1) / BN, BB / BM, 8), 256, 0, stream>>>(
      z, Wc, p, BB, CC, DD, DD / 8);
  // argmax + entropy per row
  rowstats<<<BB, 256, 0, stream>>>(p, bc, ent_new, cls);
  // scatter (ent, idx) into fixed-size class slots, counting on the fly
  scatter<<<(MM + 255) / 256, 256, 0, stream>>>(
      labels_idx, cls, ent_in, ent_new, cnt, ent_s, idx_s);
  // per-class selection + normalized accumulation + column norm
  class_weights<<<CC, 256, 0, stream>>>(supports_in, z, ent_s, idx_s, cnt, wn);
  // out = z @ wn^T, split-K 8
  gemm_abt<<<dim3((CC + BN - 1) / BN, BB / BM, 8), 256, 0, stream>>>(
      z, wn, out, BB, CC, DD, DD / 8);
}

// Round 3
// 238.585 us; speedup vs baseline: 1.5085x; 1.5085x over previous
//
#include <hip/hip_runtime.h>
#include <hip/hip_bf16.h>
#include <math.h>

// Problem constants (fixed by setup_inputs)
#define BB   256
#define DIN  2048
#define DD   512
#define CC   1000
#define NN   50000
#define MM   (NN + BB)     // 50256
#define FILTER_K 100
#define SLOT 512           // per-class scatter capacity; max real count ~85+256

#define SK1  16            // split-K for z = x@Wf     (K=2048 -> klen 128)
#define SK2  8             // split-K for p/out = z@B^T (K=512 -> klen 64)

// ---------------- workspace layout (float elements) ----------------
#define Z_OFF     0                          // z:   [256][512]
#define CNT_OFF   (Z_OFF + BB*DD)            // cnt: [1024] int
#define ENTN_OFF  (CNT_OFF + 1024)           // ent_new: [256]
#define CLS_OFF   (ENTN_OFF + BB)            // cls: [256] int
#define ENTS_OFF  (CLS_OFF + BB)             // ent_s: [1000][512]
#define IDXS_OFF  (ENTS_OFF + CC*SLOT)       // idx_s: [1000][512] int
#define WN_OFF    (IDXS_OFF + CC*SLOT)       // wn:  [1000][512]
#define ZP_OFF    (WN_OFF + CC*DD)           // zpart: [SK1][256][512]
#define PP_OFF    (ZP_OFF + SK1*BB*DD)       // ppart: [SK2][256][1000]
#define OP_OFF    (PP_OFF + SK2*BB*CC)       // opart: [SK2][256][1000]
// total ~8.1M floats ~33 MB (< 400 MB ws)

// GEMM tiling: 64x128 block tile, 4x8 micro-tile (4 + 4 cols 64 apart),
// BK=16, split-K into PARTIAL BUFFERS (plain stores — atomics serialize at
// the memory-side coherence point on gfx950: 65 MB WRITE_SIZE, 88 us).
#define BM 64
#define BN 128
#define BK 16

// ===== K1: zpart[s] = x @ Wf (k-slice s)  A:[M][K] B:[K][N] ==============
__global__ __launch_bounds__(256, 2) void gemm_ab_part(
    const float* __restrict__ A, const float* __restrict__ B,
    float* __restrict__ Cp, int M, int N, int K, int klen) {
  __shared__ float As[BK][BM + 4];
  __shared__ float Bs[BK][BN + 4];
  const int tid = threadIdx.x;
  const int m0 = blockIdx.y * BM;
  const int n0 = blockIdx.x * BN;
  const int k0 = blockIdx.z * klen;
  const int ar = tid >> 2, ac = (tid & 3) * 4;   // A: 64 rows x 16 k
  const int br = tid >> 4, bc = (tid & 15) * 8;  // B: 16 k x 128 n
  const int tm = (tid >> 4) * 4;
  const int tn = (tid & 15) * 4;
  float acc[4][8] = {};
  for (int kk = 0; kk < klen; kk += BK) {
    float4 av  = *(const float4*)&A[(size_t)(m0 + ar) * K + (k0 + kk + ac)];
    float4 bv0 = *(const float4*)&B[(size_t)(k0 + kk + br) * N + (n0 + bc)];
    float4 bv1 = *(const float4*)&B[(size_t)(k0 + kk + br) * N + (n0 + bc + 4)];
    __syncthreads();
    As[ac + 0][ar] = av.x; As[ac + 1][ar] = av.y;
    As[ac + 2][ar] = av.z; As[ac + 3][ar] = av.w;
    *(float4*)&Bs[br][bc] = bv0;
    *(float4*)&Bs[br][bc + 4] = bv1;
    __syncthreads();
#pragma unroll
    for (int q = 0; q < BK; ++q) {
      float4 a  = *(const float4*)&As[q][tm];
      float4 b0 = *(const float4*)&Bs[q][tn];
      float4 b1 = *(const float4*)&Bs[q][tn + 64];
      float aa[4] = {a.x, a.y, a.z, a.w};
      float bb[8] = {b0.x, b0.y, b0.z, b0.w, b1.x, b1.y, b1.z, b1.w};
#pragma unroll
      for (int i = 0; i < 4; ++i)
#pragma unroll
        for (int j = 0; j < 8; ++j) acc[i][j] += aa[i] * bb[j];
    }
  }
  float* Cb = Cp + (size_t)blockIdx.z * M * N;
#pragma unroll
  for (int i = 0; i < 4; ++i) {
    *(float4*)&Cb[(size_t)(m0 + tm + i) * N + (n0 + tn)] =
        make_float4(acc[i][0], acc[i][1], acc[i][2], acc[i][3]);
    *(float4*)&Cb[(size_t)(m0 + tm + i) * N + (n0 + 64 + tn)] =
        make_float4(acc[i][4], acc[i][5], acc[i][6], acc[i][7]);
  }
}

// ==== K2/K5: Cp[s] = A @ B^T (k-slice s)  A:[M][K] B:[L][K], L-guard =====
__global__ __launch_bounds__(256, 2) void gemm_abt_part(
    const float* __restrict__ A, const float* __restrict__ B,
    float* __restrict__ Cp, int M, int L, int K, int klen) {
  __shared__ float As[BK][BM + 4];
  __shared__ float Bs[BK][BN + 4];
  const int tid = threadIdx.x;
  const int m0 = blockIdx.y * BM;
  const int n0 = blockIdx.x * BN;
  const int k0 = blockIdx.z * klen;
  const int ar = tid >> 2, ac = (tid & 3) * 4;   // A: 64 rows x 16 k
  const int br = tid >> 2, bc = (tid & 3) * 4;   // B: 2 x (64 rows) x 16 k
  const int tm = (tid >> 4) * 4;
  const int tn = (tid & 15) * 4;
  float acc[4][8] = {};
  for (int kk = 0; kk < klen; kk += BK) {
    float4 av = *(const float4*)&A[(size_t)(m0 + ar) * K + (k0 + kk + ac)];
    float4 bv0 = make_float4(0.f, 0.f, 0.f, 0.f);
    float4 bv1 = make_float4(0.f, 0.f, 0.f, 0.f);
    if (n0 + br < L)
      bv0 = *(const float4*)&B[(size_t)(n0 + br) * K + (k0 + kk + bc)];
    if (n0 + 64 + br < L)
      bv1 = *(const float4*)&B[(size_t)(n0 + 64 + br) * K + (k0 + kk + bc)];
    __syncthreads();
    As[ac + 0][ar] = av.x; As[ac + 1][ar] = av.y;
    As[ac + 2][ar] = av.z; As[ac + 3][ar] = av.w;
    Bs[bc + 0][br] = bv0.x; Bs[bc + 1][br] = bv0.y;
    Bs[bc + 2][br] = bv0.z; Bs[bc + 3][br] = bv0.w;
    Bs[bc + 0][br + 64] = bv1.x; Bs[bc + 1][br + 64] = bv1.y;
    Bs[bc + 2][br + 64] = bv1.z; Bs[bc + 3][br + 64] = bv1.w;
    __syncthreads();
#pragma unroll
    for (int q = 0; q < BK; ++q) {
      float4 a  = *(const float4*)&As[q][tm];
      float4 b0 = *(const float4*)&Bs[q][tn];
      float4 b1 = *(const float4*)&Bs[q][tn + 64];
      float aa[4] = {a.x, a.y, a.z, a.w};
      float bb[8] = {b0.x, b0.y, b0.z, b0.w, b1.x, b1.y, b1.z, b1.w};
#pragma unroll
      for (int i = 0; i < 4; ++i)
#pragma unroll
        for (int j = 0; j < 8; ++j) acc[i][j] += aa[i] * bb[j];
    }
  }
  float* Cb = Cp + (size_t)blockIdx.z * M * L;
#pragma unroll
  for (int i = 0; i < 4; ++i)
#pragma unroll
    for (int j = 0; j < 4; ++j) {
      int n = n0 + tn + j;
      if (n < L) Cb[(size_t)(m0 + tm + i) * L + n] = acc[i][j];
      int n2 = n0 + 64 + tn + j;
      if (n2 < L) Cb[(size_t)(m0 + tm + i) * L + n2] = acc[i][j + 4];
    }
}

// ============ elementwise reduction of S split-K partials ================
template <int S>
__global__ __launch_bounds__(256) void reduce_part(
    const float* __restrict__ part, float* __restrict__ out, int n4) {
  int i = blockIdx.x * 256 + threadIdx.x;
  if (i >= n4) return;
  const float4* p4 = (const float4*)part;
  float4 a = p4[i];
#pragma unroll
  for (int s = 1; s < S; ++s) {
    float4 b = p4[(size_t)s * n4 + i];
    a.x += b.x; a.y += b.y; a.z += b.z; a.w += b.w;
  }
  ((float4*)out)[i] = a;
}

// == per-row argmax + entropy; sums the SK2 p-partials + bias on the fly ==
__global__ __launch_bounds__(256) void rowstats(
    const float* __restrict__ ppart, const float* __restrict__ bc,
    float* __restrict__ ent_new, int* __restrict__ cls) {
  const int b = blockIdx.x, tid = threadIdx.x;
  const int lane = tid & 63, wid = tid >> 6;
  float r[4];
  float mv = -INFINITY; int mi = 0x7fffffff;
#pragma unroll
  for (int i = 0; i < 4; ++i) {
    int c = tid + 256 * i;
    if (c < CC) {
      float v = bc[c];
#pragma unroll
      for (int s = 0; s < SK2; ++s)
        v += ppart[(size_t)s * BB * CC + (size_t)b * CC + c];
      r[i] = v;
    } else {
      r[i] = -INFINITY;
    }
    if (r[i] > mv) { mv = r[i]; mi = c; }   // ascending c: strict > keeps first
  }
#pragma unroll
  for (int o = 32; o > 0; o >>= 1) {
    float ov = __shfl_down(mv, o, 64);
    int oi = __shfl_down(mi, o, 64);
    if (ov > mv || (ov == mv && oi < mi)) { mv = ov; mi = oi; }
  }
  __shared__ float smv[4]; __shared__ int smi[4];
  if (lane == 0) { smv[wid] = mv; smi[wid] = mi; }
  __syncthreads();
  if (tid == 0) {
#pragma unroll
    for (int w = 1; w < 4; ++w)
      if (smv[w] > smv[0] || (smv[w] == smv[0] && smi[w] < smi[0])) {
        smv[0] = smv[w]; smi[0] = smi[w];
      }
  }
  __syncthreads();
  const float m = smv[0]; const int am = smi[0];
  float s = 0.f, t = 0.f;
#pragma unroll
  for (int i = 0; i < 4; ++i) {
    if (tid + 256 * i < CC) {
      float u = r[i] - m;
      float e = expf(u);
      s += e; t += u * e;
    }
  }
#pragma unroll
  for (int o = 32; o > 0; o >>= 1) {
    s += __shfl_down(s, o, 64);
    t += __shfl_down(t, o, 64);
  }
  __shared__ float ssum[4], tsum[4];
  if (lane == 0) { ssum[wid] = s; tsum[wid] = t; }
  __syncthreads();
  if (tid == 0) {
    float S = ssum[0] + ssum[1] + ssum[2] + ssum[3];
    float T = tsum[0] + tsum[1] + tsum[2] + tsum[3];
    ent_new[b] = logf(S) - T / S;
    cls[b] = am;
  }
}

// ========== direct scatter into fixed per-class slots (no scan) ==========
__global__ void scatter(const int* __restrict__ labels_idx,
                        const int* __restrict__ cls,
                        const float* __restrict__ ent_in,
                        const float* __restrict__ ent_new,
                        int* __restrict__ cnt,
                        float* __restrict__ ent_s, int* __restrict__ idx_s) {
  int m = blockIdx.x * blockDim.x + threadIdx.x;
  if (m >= MM) return;
  int c; float e;
  if (m < NN) { c = labels_idx[m]; e = ent_in[m]; }
  else        { c = cls[m - NN];   e = ent_new[m - NN]; }
  int pos = atomicAdd(&cnt[c], 1);
  if (pos < SLOT) {
    ent_s[(size_t)c * SLOT + pos] = e;
    idx_s[(size_t)c * SLOT + pos] = m;
  }
}

// ====== per-class: select K lowest-entropy rows, sum normalized rows =====
// Wave-per-row: no barriers in the streaming loop; full-wave shfl_xor reduce.
__global__ __launch_bounds__(256) void class_weights(
    const float* __restrict__ supports_in, const float* __restrict__ z,
    const float* __restrict__ ent_s, const int* __restrict__ idx_s,
    const int* __restrict__ cnt, float* __restrict__ wn) {
  const int c = blockIdx.x, tid = threadIdx.x;
  const int lane = tid & 63, wid = tid >> 6;
  int n = cnt[c]; if (n > SLOT) n = SLOT;

  __shared__ int sel[SLOT];
  __shared__ float se[SLOT];
  __shared__ int si[SLOT];
  int seln;
  if (n <= FILTER_K) {
    seln = n;
    for (int i = tid; i < n; i += 256) sel[i] = idx_s[(size_t)c * SLOT + i];
  } else {
    for (int i = tid; i < SLOT; i += 256) {
      if (i < n) { se[i] = ent_s[(size_t)c * SLOT + i]; si[i] = idx_s[(size_t)c * SLOT + i]; }
      else       { se[i] = INFINITY;                     si[i] = 0x7fffffff; }
    }
    __syncthreads();
    for (int k = 2; k <= SLOT; k <<= 1)
      for (int j = k >> 1; j > 0; j >>= 1) {
        for (int i = tid; i < SLOT; i += 256) {
          int ixj = i ^ j;
          if (ixj > i) {
            bool up = ((i & k) == 0);
            float e1 = se[i], e2 = se[ixj];
            int i1 = si[i], i2 = si[ixj];
            bool gt = (e1 > e2) || (e1 == e2 && i1 > i2);
            if (gt == up) { se[i] = e2; se[ixj] = e1; si[i] = i2; si[ixj] = i1; }
          }
        }
        __syncthreads();
      }
    seln = FILTER_K;
    for (int i = tid; i < FILTER_K; i += 256) sel[i] = si[i];
  }
  __syncthreads();

  // each wave streams whole rows; lane owns dims [lane*8, lane*8+8)
  float4 a0 = make_float4(0.f, 0.f, 0.f, 0.f), a1 = a0;
  for (int j = wid; j < seln; j += 4) {
    int ridx = sel[j];
    const float4* p4 = (const float4*)((ridx < NN)
        ? supports_in + (size_t)ridx * DD
        : z + (size_t)(ridx - NN) * DD);
    float4 v0 = p4[lane * 2], v1 = p4[lane * 2 + 1];
    float s = v0.x * v0.x + v0.y * v0.y + v0.z * v0.z + v0.w * v0.w
            + v1.x * v1.x + v1.y * v1.y + v1.z * v1.z + v1.w * v1.w;
#pragma unroll
    for (int o = 1; o < 64; o <<= 1) s += __shfl_xor(s, o, 64);
    float sc = 1.0f / fmaxf(sqrtf(s), 1e-12f);
    a0.x += v0.x * sc; a0.y += v0.y * sc; a0.z += v0.z * sc; a0.w += v0.w * sc;
    a1.x += v1.x * sc; a1.y += v1.y * sc; a1.z += v1.z * sc; a1.w += v1.w * sc;
  }

  __shared__ float part[4][DD];
  *(float4*)&part[wid][lane * 8] = a0;
  *(float4*)&part[wid][lane * 8 + 4] = a1;
  __syncthreads();
  const int d = tid * 2;
  float2 w;
  w.x = part[0][d] + part[1][d] + part[2][d] + part[3][d];
  w.y = part[0][d + 1] + part[1][d + 1] + part[2][d + 1] + part[3][d + 1];
  float ss = w.x * w.x + w.y * w.y;
#pragma unroll
  for (int o = 1; o < 64; o <<= 1) ss += __shfl_xor(ss, o, 64);
  __shared__ float tot[4];
  if (lane == 0) tot[wid] = ss;
  __syncthreads();
  float S = tot[0] + tot[1] + tot[2] + tot[3];
  float sc = 1.0f / fmaxf(sqrtf(S), 1e-12f);
  ((float2*)(wn + (size_t)c * DD))[tid] = make_float2(w.x * sc, w.y * sc);
}

// ============================ launcher ===================================
extern "C" void kernel_launch(void* const* d_in, const int* in_sizes, int n_in,
                              void* d_out, int out_size, void* d_ws, size_t ws_size,
                              hipStream_t stream) {
  (void)in_sizes; (void)n_in; (void)out_size; (void)ws_size;
  const float* x           = (const float*)d_in[0];
  const float* Wf          = (const float*)d_in[1];
  const float* Wc          = (const float*)d_in[2];
  const float* bc          = (const float*)d_in[3];
  const float* supports_in = (const float*)d_in[4];
  const float* ent_in      = (const float*)d_in[5];
  const int*   labels_idx  = (const int*)d_in[6];
  float* out = (float*)d_out;

  float* W = (float*)d_ws;
  float* z       = W + Z_OFF;
  int*   cnt     = (int*)(W + CNT_OFF);
  float* ent_new = W + ENTN_OFF;
  int*   cls     = (int*)(W + CLS_OFF);
  float* ent_s   = W + ENTS_OFF;
  int*   idx_s   = (int*)(W + IDXS_OFF);
  float* wn      = W + WN_OFF;
  float* zpart   = W + ZP_OFF;
  float* ppart   = W + PP_OFF;
  float* opart   = W + OP_OFF;

  // only the class counters need zeroing (4 KB)
  hipMemsetAsync(cnt, 0, 1024 * sizeof(int), stream);

  // z = x @ Wf: 16-way split-K partials (256 blocks), then reduce
  gemm_ab_part<<<dim3(DD / BN, BB / BM, SK1), 256, 0, stream>>>(
      x, Wf, zpart, BB, DD, DIN, DIN / SK1);
  reduce_part<SK1><<<(BB * DD / 4 + 255) / 256, 256, 0, stream>>>(
      zpart, z, BB * DD / 4);

  // p partials = z @ Wc^T (8-way split-K, 256 blocks); bias+reduce in rowstats
  gemm_abt_part<<<dim3((CC + BN - 1) / BN, BB / BM, SK2), 256, 0, stream>>>(
      z, Wc, ppart, BB, CC, DD, DD / SK2);
  rowstats<<<BB, 256, 0, stream>>>(ppart, bc, ent_new, cls);

  // scatter (ent, idx) into fixed-size class slots, counting on the fly
  scatter<<<(MM + 255) / 256, 256, 0, stream>>>(
      labels_idx, cls, ent_in, ent_new, cnt, ent_s, idx_s);
  // per-class selection + normalized accumulation + column norm
  class_weights<<<CC, 256, 0, stream>>>(supports_in, z, ent_s, idx_s, cnt, wn);

  // out partials = z @ wn^T, then reduce into d_out
  gemm_abt_part<<<dim3((CC + BN - 1) / BN, BB / BM, SK2), 256, 0, stream>>>(
      z, wn, opart, BB, CC, DD, DD / SK2);
  reduce_part<SK2><<<(BB * CC / 4 + 255) / 256, 256, 0, stream>>>(
      opart, out, BB * CC / 4);
}